// Round 17
// baseline (34.291 us; speedup 1.0000x reference)
//
#include <hip/hip_runtime.h>

namespace {

constexpr int kT   = 8;    // timesteps
constexpr int kB   = 256;  // batch
constexpr int kNQ  = 8;    // qubits per circuit
constexpr int kNB  = 8;    // blocks
constexpr int kD   = 64;   // features
constexpr int kNL  = 2;    // quantum layers
constexpr int kGateF = 8;
constexpr int kCircStride = 16 * kGateF + 4;   // 132: pad so u-strides hit distinct banks

// Walsh parity masks (validated r4-r16): wire-set of output w, bit j = wire j.
// g0={2,4,6} g1={3,5,7} g2={0,2} g3={1,3} g4={0,2,4} g5={1,3,5} g6={0,2,4,6} g7={1,3,5,7}
constexpr unsigned long long kMaskPacked =
    (0x54ULL << 0) | (0xA8ULL << 8) | (0x05ULL << 16) | (0x0AULL << 24) |
    (0x15ULL << 32) | (0x2AULL << 40) | (0x55ULL << 48) | (0xAAULL << 56);

// ---------------- fast sincos of a/2 ----------------
// v_sin/v_cos take REVOLUTIONS; |a| small here -> no range reduction needed.
__device__ __forceinline__ void fastsc(float a, float& s, float& c) {
#if __has_builtin(__builtin_amdgcn_sinf) && __has_builtin(__builtin_amdgcn_cosf)
    const float r = a * 0.07957747154594767f;   // 0.5 / (2*pi)
    s = __builtin_amdgcn_sinf(r);
    c = __builtin_amdgcn_cosf(r);
#else
    __sincosf(0.5f * a, &s, &c);
#endif
}

// B_j entry select: h_j if wire j in mask, else identity.
__device__ __forceinline__ void bsel(const float* __restrict__ hh, int j, unsigned mask,
                                     float& b00, float& b01r, float& b01i, float& b11) {
    const float* hp = hh + j * kGateF;
    const bool m = (mask >> j) & 1u;
    const float a = hp[0], hr = hp[1], hi = hp[2];
    b00  = m ? a   : 1.0f;
    b01r = m ? hr  : 0.0f;
    b01i = m ? hi  : 0.0f;
    b11  = m ? -a  : 1.0f;
}

// rho[a][ap] fetch with RUNTIME a,ap from the four entry values (no array indexing)
__device__ __forceinline__ void rho_rt(float r00, float r11, float r01r, float r01i,
                                       int a, int ap, float& rr, float& ri) {
    const bool eq = (a == ap);
    rr = eq ? (a ? r11 : r00) : r01r;
    ri = eq ? 0.0f : (a ? -r01i : r01i);
}

// ---------------- one bb-slice of the 16-state transfer-matrix DP ----------------
// Full DP (validated r15/r16): E_w = sum over (b0,b'0) slices of independent
// 4-complex-state chains. This computes ONE slice (b0,bp), caller sums 4 slices.
// l = ring1(b): l_j = b_0^..^b_j (j>=1), l_0 = total^b_0.
__device__ __forceinline__ float simdp_slice(const float (&ang)[8],
                                             const float* __restrict__ g0,  // d0 gates (LDS)
                                             const float* __restrict__ hh,  // d1 herms (LDS)
                                             unsigned mask, int b0, int bp) {
    // per-wire density-matrix entries: rho = sigma sigma^dag,
    // sigma_j = Rot0_j * RY(ang_j)|0>
    float r00[8], r11[8], r01r[8], r01i[8];
#pragma unroll
    for (int j = 0; j < 8; ++j) {
        float sn, cs;
        fastsc(ang[j], sn, cs);
        const float* gp = g0 + j * kGateF;
        const float s0r = gp[0] * cs + gp[2] * sn, s0i = gp[1] * cs + gp[3] * sn;
        const float s1r = gp[4] * cs + gp[6] * sn, s1i = gp[5] * cs + gp[7] * sn;
        r00[j]  = s0r * s0r + s0i * s0i;
        r11[j]  = s1r * s1r + s1i * s1i;
        r01r[j] = s0r * s1r + s0i * s1i;   // sigma0 * conj(sigma1)
        r01i[j] = s0i * s1r - s0r * s1i;
    }

    float Vr[2][2], Vi[2][2];   // [p][p'] for this slice

    // init fused with step j=1: V = rho0[b0,bp] * rho1[p^b0, p'^bp] * B1[p'][p]
    {
        float b00, b01r, b01i, b11;
        bsel(hh, 1, mask, b00, b01r, b01i, b11);
        float q0r, q0i;
        rho_rt(r00[0], r11[0], r01r[0], r01i[0], b0, bp, q0r, q0i);
#pragma unroll
        for (int p = 0; p < 2; ++p)
#pragma unroll
        for (int pp = 0; pp < 2; ++pp) {
            float q1r, q1i;
            rho_rt(r00[1], r11[1], r01r[1], r01i[1], p ^ b0, pp ^ bp, q1r, q1i);
            const float tr = q0r * q1r - q0i * q1i;
            const float ti = q0r * q1i + q0i * q1r;
            float Br, Bi;
            if (p == pp) { Br = p ? b11 : b00; Bi = 0.0f; }
            else if (pp == 0) { Br = b01r; Bi = b01i; }      // B[0][1]
            else { Br = b01r; Bi = -b01i; }                  // B[1][0] = conj
            Vr[p][pp] = tr * Br - ti * Bi;
            Vi[p][pp] = tr * Bi + ti * Br;
        }
    }

    // steps j = 2..7: V'[p,p'] = B_j[p'][p] * sum_{q,q'} rho_j[p^q, p'^q'] V[q,q']
#pragma unroll
    for (int j = 2; j < 8; ++j) {
        float b00, b01r, b01i, b11;
        bsel(hh, j, mask, b00, b01r, b01i, b11);
        const float c00 = r00[j], c11 = r11[j], c01r = r01r[j], c01i = r01i[j];
        float nr[2][2], ni[2][2];
#pragma unroll
        for (int p = 0; p < 2; ++p)
#pragma unroll
        for (int pp = 0; pp < 2; ++pp) {
            float sr = c00 * Vr[p][pp] + c11 * Vr[p ^ 1][pp ^ 1];
            float si = c00 * Vi[p][pp] + c11 * Vi[p ^ 1][pp ^ 1];
            sr += c01r * Vr[p][pp ^ 1] - c01i * Vi[p][pp ^ 1];
            si += c01r * Vi[p][pp ^ 1] + c01i * Vr[p][pp ^ 1];
            sr += c01r * Vr[p ^ 1][pp] + c01i * Vi[p ^ 1][pp];
            si += c01r * Vi[p ^ 1][pp] - c01i * Vr[p ^ 1][pp];
            float Br, Bi;
            if (p == pp) { Br = p ? b11 : b00; Bi = 0.0f; }
            else if (pp == 0) { Br = b01r; Bi = b01i; }
            else { Br = b01r; Bi = -b01i; }
            nr[p][pp] = sr * Br - si * Bi;
            ni[p][pp] = sr * Bi + si * Br;
        }
        Vr[0][0] = nr[0][0]; Vi[0][0] = ni[0][0];
        Vr[0][1] = nr[0][1]; Vi[0][1] = ni[0][1];
        Vr[1][0] = nr[1][0]; Vi[1][0] = ni[1][0];
        Vr[1][1] = nr[1][1]; Vi[1][1] = ni[1][1];
    }

    // final: E_slice = Re sum_{p,p'} V[p][p'] * B0[p'^bp][p^b0]   (l_0 wrap)
    float E = 0.0f;
    {
        float b00, b01r, b01i, b11;
        bsel(hh, 0, mask, b00, b01r, b01i, b11);
#pragma unroll
        for (int p = 0; p < 2; ++p)
#pragma unroll
        for (int pp = 0; pp < 2; ++pp) {
            const int cc = p ^ b0;    // l_0 (ket)
            const int rr = pp ^ bp;   // l'_0 (bra)
            const bool eq = (rr == cc);
            const float Br = eq ? (cc ? b11 : b00) : b01r;
            const float Bi = eq ? 0.0f : (rr == 0 ? b01i : -b01i);
            E += Vr[p][pp] * Br - Vi[p][pp] * Bi;
        }
    }
    return E;
}

// ---------------- single fused kernel ----------------
// block = 256 threads = one (t, sample b) tile; wave = one bb slice (b0,b'0);
// lane = (u:3, w:3). Gate build into LDS (one slot/thread), then per-slice DP,
// LDS reduction over slices, layer-1 DP, reduce, store.
__global__ __launch_bounds__(256) void fused_kernel(const float* __restrict__ x,
                                                    const float* __restrict__ theta,
                                                    float* __restrict__ out) {
    __shared__ float gl[kNL * kNB * kCircStride];   // 2112 floats = 8448 B
    __shared__ float part0[4][64];
    __shared__ float part1[4][64];

    const int tid  = threadIdx.x;
    const int bb   = tid >> 6;        // slice index
    const int b0   = bb >> 1, bp = bb & 1;
    const int lane = tid & 63;
    const int tt = blockIdx.x >> 8;   // timestep (block-uniform)
    const int b  = blockIdx.x & 255;  // sample
    const int u  = lane >> 3;         // circuit within timestep
    const int w  = lane & 7;          // output wire
    const unsigned mask = (unsigned)((kMaskPacked >> (w * 8)) & 0xFF);

    // ---- gate build: one slot per thread (coalesced theta reads) ----
    {
        const int l  = tid >> 7;
        const int uu = (tid >> 4) & 7;
        const int g  = tid & 15;         // d*8 + wire
        const int d  = g >> 3, ww = g & 7;
        const float* th = theta + ((((tt * kNL + l) * kNB + uu) * 2 + d) * kNQ + ww) * 3;
        const float phi = th[0], tht = th[1], omg = th[2];
        float st, ct, sp, cp, sm, cm;
        fastsc(tht, st, ct);
        fastsc(phi + omg, sp, cp);
        fastsc(phi - omg, sm, cm);
        const float u00r =  ct * cp, u00i = -ct * sp;
        const float u01r = -st * cm, u01i = -st * sm;
        const float u10r =  st * cm, u10i = -st * sm;
        const float u11r =  ct * cp, u11i =  ct * sp;
        float* o = &gl[(l * kNB + uu) * kCircStride + g * kGateF];
        if (d == 1) {
            // h = g^dag Z g (Hermitian, traceless)
            o[0] = (u00r * u00r + u00i * u00i) - (u10r * u10r + u10i * u10i);
            o[1] = (u00r * u01r + u00i * u01i) - (u10r * u11r + u10i * u11i);
            o[2] = (u00r * u01i - u00i * u01r) - (u10r * u11i - u10i * u11r);
        } else {
            o[0] = u00r;  o[1] = u00i;
            o[2] = u01r;  o[3] = u01i;
            o[4] = u10r;  o[5] = u10i;
            o[6] = u11r;  o[7] = u11i;
        }
    }
    __syncthreads();

    // ---- phase 0: layer-0 circuit (t,u), angles from x ----
    float ang[8];
    {
        const float* ab = x + ((b * kT + tt) * kD + u * kNQ);
#pragma unroll
        for (int j = 0; j < 8; ++j) ang[j] = ab[j];
    }
    const float* base0 = &gl[u * kCircStride];
    part0[bb][lane] = simdp_slice(ang, base0, base0 + 8 * kGateF, mask, b0, bp);
    __syncthreads();

    // ---- phase-1 angles: ang[i] = E(circuit i, wire u) = sum_bb part0[bb][i*8+u]
    // (8-lane broadcast reads, conflict-free) ----
#pragma unroll
    for (int i = 0; i < 8; ++i) {
        const int s = i * 8 + u;
        ang[i] = (part0[0][s] + part0[1][s]) + (part0[2][s] + part0[3][s]);
    }

    // ---- phase 1: layer-1 circuit (t,u) ----
    const float* base1 = &gl[(kNB + u) * kCircStride];
    part1[bb][lane] = simdp_slice(ang, base1, base1 + 8 * kGateF, mask, b0, bp);
    __syncthreads();

    if (bb == 0) {
        const float Et = (part1[0][lane] + part1[1][lane]) + (part1[2][lane] + part1[3][lane]);
        out[(b * kT + tt) * kD + lane] = Et;   // 64 consecutive floats: coalesced
    }
}

}  // namespace

extern "C" void kernel_launch(void* const* d_in, const int* in_sizes, int n_in,
                              void* d_out, int out_size, void* d_ws, size_t ws_size,
                              hipStream_t stream) {
    const float* x     = (const float*)d_in[0];   // (B, T, D) fp32
    const float* theta = (const float*)d_in[1];   // (T, NL, NB, DEPTH, NQ, 3) fp32
    float* out = (float*)d_out;                   // (B, T, D) fp32

    // one block per (t, b): 2048 blocks x 4 waves = 8192 waves (32 waves/CU)
    fused_kernel<<<kT * kB, 256, 0, stream>>>(x, theta, out);
}

// Round 18
// 15.449 us; speedup vs baseline: 2.2196x; 2.2196x over previous
//
#include <hip/hip_runtime.h>

namespace {

typedef float v2f __attribute__((ext_vector_type(2)));

constexpr int kT   = 8;    // timesteps
constexpr int kB   = 256;  // batch
constexpr int kNQ  = 8;    // qubits per circuit
constexpr int kNB  = 8;    // blocks
constexpr int kD   = 64;   // features
constexpr int kNL  = 2;    // quantum layers
constexpr int kGateF = 8;
constexpr int kCircStride = 16 * kGateF + 4;   // 132: pad so u-strides hit distinct banks

// Walsh parity masks (validated r4-r17): wire-set of output w, bit j = wire j.
// g0={2,4,6} g1={3,5,7} g2={0,2} g3={1,3} g4={0,2,4} g5={1,3,5} g6={0,2,4,6} g7={1,3,5,7}
constexpr unsigned long long kMaskPacked =
    (0x54ULL << 0) | (0xA8ULL << 8) | (0x05ULL << 16) | (0x0AULL << 24) |
    (0x15ULL << 32) | (0x2AULL << 40) | (0x55ULL << 48) | (0xAAULL << 56);

__device__ __forceinline__ v2f mk(float a, float b) { v2f r; r.x = a; r.y = b; return r; }

// ---------------- fast sincos of a/2 ----------------
// v_sin/v_cos take REVOLUTIONS; |a| small here -> no range reduction needed.
__device__ __forceinline__ void fastsc(float a, float& s, float& c) {
#if __has_builtin(__builtin_amdgcn_sinf) && __has_builtin(__builtin_amdgcn_cosf)
    const float r = a * 0.07957747154594767f;   // 0.5 / (2*pi)
    s = __builtin_amdgcn_sinf(r);
    c = __builtin_amdgcn_cosf(r);
#else
    __sincosf(0.5f * a, &s, &c);
#endif
}

// B_j entry select: h_j if wire j in mask, else identity.
__device__ __forceinline__ void bsel(const float* __restrict__ hh, int j, unsigned mask,
                                     float& b00, float& b01r, float& b01i, float& b11) {
    const float* hp = hh + j * kGateF;
    const bool m = (mask >> j) & 1u;
    const float a = hp[0], hr = hp[1], hi = hp[2];
    b00  = m ? a   : 1.0f;
    b01r = m ? hr  : 0.0f;
    b01i = m ? hi  : 0.0f;
    b11  = m ? -a  : 1.0f;
}

// ---------------- 16-state transfer-matrix DP, bb-slices packed 2-per-v2f ------------
// E_w = sum over (b0,b'0) slices; chain A packs slices {(0,0),(1,1)}, chain B packs
// {(0,1),(1,0)}. The j=2..7 recurrence is slice-independent (scalar coeffs x v2f ->
// v_pk_fma); only init (j=0,1) and the l_0-wrap final differ per slice (packed
// constants below, derived per (p,p') case).  [DP validated r15/r16]
__device__ __forceinline__ float simdp(const float (&ang)[8],
                                       const float* __restrict__ g0,   // d0 gates (LDS)
                                       const float* __restrict__ hh,   // d1 herms (LDS)
                                       unsigned mask) {
    // per-wire density-matrix entries: rho = sigma sigma^dag,
    // sigma_j = Rot0_j * RY(ang_j)|0>
    float r00[8], r11[8], r01r[8], r01i[8];
#pragma unroll
    for (int j = 0; j < 8; ++j) {
        float sn, cs;
        fastsc(ang[j], sn, cs);
        const float* gp = g0 + j * kGateF;
        const float s0r = gp[0] * cs + gp[2] * sn, s0i = gp[1] * cs + gp[3] * sn;
        const float s1r = gp[4] * cs + gp[6] * sn, s1i = gp[5] * cs + gp[7] * sn;
        r00[j]  = s0r * s0r + s0i * s0i;
        r11[j]  = s1r * s1r + s1i * s1i;
        r01r[j] = s0r * s1r + s0i * s1i;   // sigma0 * conj(sigma1)
        r01i[j] = s0i * s1r - s0r * s1i;
    }

    v2f VAr[2][2], VAi[2][2], VBr[2][2], VBi[2][2];

    // ---- init fused with step j=1: V = rho0[b0,b'0] * rho1[p^b0, p'^b'0] * B1[p'][p]
    {
        float b00, b01r, b01i, b11;
        bsel(hh, 1, mask, b00, b01r, b01i, b11);
        const v2f q0Ar = mk(r00[0], r11[0]);                 // rho0 diag (real)
        const v2f q0Br = mk(r01r[0], r01r[0]);               // rho0 off-diag
        const v2f q0Bi = mk(r01i[0], -r01i[0]);
#pragma unroll
        for (int p = 0; p < 2; ++p)
#pragma unroll
        for (int pp = 0; pp < 2; ++pp) {
            // scalar B1[pp][p]
            float B1r, B1i;
            if (p == pp) { B1r = p ? b11 : b00; B1i = 0.0f; }
            else if (pp == 0) { B1r = b01r; B1i = b01i; }
            else { B1r = b01r; B1i = -b01i; }
            // chain A: m1 = {rho1[p][pp], rho1[p^1][pp^1]}
            v2f m1r, m1i;
            if (p == pp) {
                m1r = p ? mk(r11[1], r00[1]) : mk(r00[1], r11[1]);
                m1i = mk(0.0f, 0.0f);
            } else if (p == 0) { m1r = mk(r01r[1], r01r[1]); m1i = mk(r01i[1], -r01i[1]); }
            else               { m1r = mk(r01r[1], r01r[1]); m1i = mk(-r01i[1], r01i[1]); }
            {
                const v2f tr = q0Ar * m1r;           // q0A is real
                const v2f ti = q0Ar * m1i;
                VAr[p][pp] = tr * B1r - ti * B1i;
                VAi[p][pp] = tr * B1i + ti * B1r;
            }
            // chain B: m1 = {rho1[p][pp^1], rho1[p^1][pp]}
            if (p != pp) {
                m1r = (p == 0) ? mk(r00[1], r11[1]) : mk(r11[1], r00[1]);
                m1i = mk(0.0f, 0.0f);
            } else if (p == 0) { m1r = mk(r01r[1], r01r[1]); m1i = mk(r01i[1], -r01i[1]); }
            else               { m1r = mk(r01r[1], r01r[1]); m1i = mk(-r01i[1], r01i[1]); }
            {
                const v2f tr = q0Br * m1r - q0Bi * m1i;
                const v2f ti = q0Br * m1i + q0Bi * m1r;
                VBr[p][pp] = tr * B1r - ti * B1i;
                VBi[p][pp] = tr * B1i + ti * B1r;
            }
        }
    }

    // ---- steps j = 2..7: V'[p,p'] = B_j[p'][p] * sum_{q,q'} rho_j[p^q,p'^q'] V[q,q']
    // (slice-independent recurrence: scalar coeffs broadcast over v2f)
#pragma unroll
    for (int j = 2; j < 8; ++j) {
        float b00, b01r, b01i, b11;
        bsel(hh, j, mask, b00, b01r, b01i, b11);
        const float c00 = r00[j], c11 = r11[j], c01r = r01r[j], c01i = r01i[j];
#define DP_STEP(Vr, Vi)                                                        \
        {                                                                      \
            v2f nr[2][2], ni[2][2];                                            \
            _Pragma("unroll")                                                  \
            for (int p = 0; p < 2; ++p)                                        \
                _Pragma("unroll")                                              \
                for (int pp = 0; pp < 2; ++pp) {                               \
                    v2f sr = c00 * Vr[p][pp] + c11 * Vr[p ^ 1][pp ^ 1];        \
                    v2f si = c00 * Vi[p][pp] + c11 * Vi[p ^ 1][pp ^ 1];        \
                    sr += c01r * Vr[p][pp ^ 1] - c01i * Vi[p][pp ^ 1];         \
                    si += c01r * Vi[p][pp ^ 1] + c01i * Vr[p][pp ^ 1];         \
                    sr += c01r * Vr[p ^ 1][pp] + c01i * Vi[p ^ 1][pp];         \
                    si += c01r * Vi[p ^ 1][pp] - c01i * Vr[p ^ 1][pp];         \
                    float Br, Bi;                                              \
                    if (p == pp) { Br = p ? b11 : b00; Bi = 0.0f; }            \
                    else if (pp == 0) { Br = b01r; Bi = b01i; }                \
                    else { Br = b01r; Bi = -b01i; }                            \
                    nr[p][pp] = sr * Br - si * Bi;                             \
                    ni[p][pp] = sr * Bi + si * Br;                             \
                }                                                              \
            Vr[0][0] = nr[0][0]; Vi[0][0] = ni[0][0];                          \
            Vr[0][1] = nr[0][1]; Vi[0][1] = ni[0][1];                          \
            Vr[1][0] = nr[1][0]; Vi[1][0] = ni[1][0];                          \
            Vr[1][1] = nr[1][1]; Vi[1][1] = ni[1][1];                          \
        }
        DP_STEP(VAr, VAi)
        DP_STEP(VBr, VBi)
#undef DP_STEP
    }

    // ---- final l_0 wrap: E = Re sum V[p][p'] * B0[p'^b'0][p^b0], packed per chain ----
    v2f acc = mk(0.0f, 0.0f);
    {
        float b00, b01r, b01i, b11;
        bsel(hh, 0, mask, b00, b01r, b01i, b11);
#pragma unroll
        for (int p = 0; p < 2; ++p)
#pragma unroll
        for (int pp = 0; pp < 2; ++pp) {
            // chain A: B = {B0[pp][p], B0[pp^1][p^1]}
            v2f Br, Bi;
            if (p == pp) { Br = p ? mk(b11, b00) : mk(b00, b11); Bi = mk(0.0f, 0.0f); }
            else if (p == 0) { Br = mk(b01r, b01r); Bi = mk(-b01i, b01i); }  // (0,1)
            else             { Br = mk(b01r, b01r); Bi = mk(b01i, -b01i); }  // (1,0)
            acc += VAr[p][pp] * Br - VAi[p][pp] * Bi;
            // chain B: B = {B0[pp^1][p], B0[pp][p^1]}
            if (p != pp) { Br = (p == 0) ? mk(b00, b11) : mk(b11, b00); Bi = mk(0.0f, 0.0f); }
            else if (p == 0) { Br = mk(b01r, b01r); Bi = mk(-b01i, b01i); }  // (0,0)
            else             { Br = mk(b01r, b01r); Bi = mk(b01i, -b01i); }  // (1,1)
            acc += VBr[p][pp] * Br - VBi[p][pp] * Bi;
        }
    }
    return acc.x + acc.y;
}

// ---------------- single fused kernel: gate build (LDS) + both layers ----------------
// block = 256 threads = 4 waves, all sharing one timestep tt (256 wids/tt).
// Gate build: thread i computes ONE gate slot (l,u,d,w) into LDS (theta reads
// coalesced). One barrier. Then: wave = (t, sample b); lane = (u:3, w:3) computes
// expval w of circuit u via the packed DP; in-wave shfl exchange between layers.
__global__ __launch_bounds__(256) void fused_kernel(const float* __restrict__ x,
                                                    const float* __restrict__ theta,
                                                    float* __restrict__ out) {
    __shared__ float gl[kNL * kNB * kCircStride];   // 2112 floats = 8448 B

    const int tid  = threadIdx.x;
    const int wid  = blockIdx.x * 4 + (tid >> 6);
    const int lane = tid & 63;
    const int tt = wid >> 8;          // timestep (block-uniform)
    const int b  = wid & 255;         // sample
    const int u  = lane >> 3;         // circuit within timestep
    const int w  = lane & 7;          // output wire
    const unsigned mask = (unsigned)((kMaskPacked >> (w * 8)) & 0xFF);

    // ---- gate build: one slot per thread ----
    {
        const int l  = tid >> 7;
        const int uu = (tid >> 4) & 7;
        const int g  = tid & 15;         // d*8 + wire
        const int d  = g >> 3, ww = g & 7;
        const float* th = theta + ((((tt * kNL + l) * kNB + uu) * 2 + d) * kNQ + ww) * 3;
        const float phi = th[0], tht = th[1], omg = th[2];
        float st, ct, sp, cp, sm, cm;
        fastsc(tht, st, ct);
        fastsc(phi + omg, sp, cp);
        fastsc(phi - omg, sm, cm);
        const float u00r =  ct * cp, u00i = -ct * sp;
        const float u01r = -st * cm, u01i = -st * sm;
        const float u10r =  st * cm, u10i = -st * sm;
        const float u11r =  ct * cp, u11i =  ct * sp;
        float* o = &gl[(l * kNB + uu) * kCircStride + g * kGateF];
        if (d == 1) {
            // h = g^dag Z g (Hermitian, traceless)
            o[0] = (u00r * u00r + u00i * u00i) - (u10r * u10r + u10i * u10i);
            o[1] = (u00r * u01r + u00i * u01i) - (u10r * u11r + u10i * u11i);
            o[2] = (u00r * u01i - u00i * u01r) - (u10r * u11i - u10i * u11r);
        } else {
            o[0] = u00r;  o[1] = u00i;
            o[2] = u01r;  o[3] = u01i;
            o[4] = u10r;  o[5] = u10i;
            o[6] = u11r;  o[7] = u11i;
        }
    }
    __syncthreads();

    // ---- phase 0: layer-0 circuit (t,u), angles from x ----
    float ang[8];
    {
        const float* ab = x + ((b * kT + tt) * kD + u * kNQ);
#pragma unroll
        for (int j = 0; j < 8; ++j) ang[j] = ab[j];
    }
    const float* base0 = &gl[u * kCircStride];
    float E = simdp(ang, base0, base0 + 8 * kGateF, mask);

    // ---- redistribute: layer-1 circuit u needs H0[t,b,i*8+u] = lane i*8+u ----
#pragma unroll
    for (int i = 0; i < 8; ++i) ang[i] = __shfl(E, i * 8 + u, 64);

    // ---- phase 1: layer-1 circuit (t,u) ----
    const float* base1 = &gl[(kNB + u) * kCircStride];
    E = simdp(ang, base1, base1 + 8 * kGateF, mask);

    out[(b * kT + tt) * kD + u * kNQ + w] = E;   // coalesced: 64 consecutive floats/wave
}

}  // namespace

extern "C" void kernel_launch(void* const* d_in, const int* in_sizes, int n_in,
                              void* d_out, int out_size, void* d_ws, size_t ws_size,
                              hipStream_t stream) {
    const float* x     = (const float*)d_in[0];   // (B, T, D) fp32
    const float* theta = (const float*)d_in[1];   // (T, NL, NB, DEPTH, NQ, 3) fp32
    float* out = (float*)d_out;                   // (B, T, D) fp32

    // single kernel: 8 timesteps x 256 samples = 2048 waves; 4 waves/block
    fused_kernel<<<kT * kB / 4, 256, 0, stream>>>(x, theta, out);
}